// Round 1
// baseline (763.611 us; speedup 1.0000x reference)
//
#include <hip/hip_runtime.h>
#include <cstddef>

// ---------------------------------------------------------------------------
// MTCNN P-Net forward, fp32, NCHW.
//   x[16,3,720,720] -> norm -> conv1(3->10,3x3)+PReLU -> maxpool2
//     -> conv2(10->16,3x3)+PReLU -> conv3(16->32,3x3)+PReLU
//     -> {conv41(32->2,1x1)+softmax, conv42(32->4,1x1)}
//   out = concat(reg[16,4,355,355], prob[16,2,355,355]) flat fp32
// ---------------------------------------------------------------------------

#define H1 718   // conv1 out spatial (720-2)
#define PH 359   // pooled spatial (718/2)
#define H2 357   // conv2 out spatial (359-2)
#define H3 355   // conv3 out spatial (357-2)

// workspace layout (float offsets)
#define W1R_OFF 0              // 270  (10*3*3*3), pre-scaled by 1/128
#define B1R_OFF 288            // 10   (norm folded in)
#define W2R_OFF 320            // 1440 (reordered [k][co], k=ci*9+kh*3+kw)
#define W3R_OFF 1792           // 4608 (reordered [k][co])
#define POOL_OFF 6400          // 16*10*359*359 = 20620960
#define C2O_OFF (POOL_OFF + (size_t)16*10*PH*PH)   // 16*16*357*357 = 32626944

// ---------------------------------------------------------------------------
// Weight repack: fold input normalization into conv1, transpose conv2/conv3
// weights to k-major / c_out-minor so the per-(ci,kh,kw) weight vector is a
// contiguous (wave-uniform) 16/32-float block.
// ---------------------------------------------------------------------------
__global__ void repack_kernel(const float* __restrict__ w1, const float* __restrict__ b1,
                              const float* __restrict__ w2, const float* __restrict__ w3,
                              float* __restrict__ ws) {
    int t = threadIdx.x;
    float* w1r = ws + W1R_OFF;
    float* b1r = ws + B1R_OFF;
    float* w2r = ws + W2R_OFF;
    float* w3r = ws + W3R_OFF;
    const float S = 0.0078125f;   // 1/128
    // conv1 weights scaled: conv((x-127.5)*S, w) == conv(x, S*w) - 127.5*S*sum(w)
    for (int i = t; i < 270; i += blockDim.x) w1r[i] = w1[i] * S;
    if (t < 10) {
        float s = 0.f;
        for (int i = 0; i < 27; i++) s += w1[t * 27 + i];
        b1r[t] = b1[t] - 127.5f * S * s;
    }
    // w2: [16,10,3,3] -> w2r[k*16+co], k = ci*9+kh*3+kw
    for (int i = t; i < 1440; i += blockDim.x) {
        int co = i & 15, k = i >> 4;
        w2r[i] = w2[co * 90 + k];
    }
    // w3: [32,16,3,3] -> w3r[k*32+co], k = ci*9+kh*3+kw
    for (int i = t; i < 4608; i += blockDim.x) {
        int co = i & 31, k = i >> 5;
        w3r[i] = w3[co * 144 + k];
    }
}

// ---------------------------------------------------------------------------
// Stage 1: (normalized) conv1 3x3 + bias + PReLU + maxpool 2x2, fused.
// One thread per pooled output pixel: 4x4x3 input window -> 4 conv sums ->
// PReLU each -> max. conv1 output (330 MB) is never materialized.
// grid: (ceil(359/128), 359, 16*10), block 128
// ---------------------------------------------------------------------------
__global__ void conv1_pool_kernel(const float* __restrict__ x,
                                  const float* __restrict__ ws,
                                  const float* __restrict__ a1,
                                  float* __restrict__ pooled) {
    int pw = blockIdx.x * blockDim.x + threadIdx.x;
    int ph = blockIdx.y;
    int z  = blockIdx.z;            // n*10 + c, wave-uniform
    if (pw >= PH) return;
    int n = z / 10, c = z % 10;
    const float* wp = ws + W1R_OFF + c * 27;
    float s00 = 0.f, s01 = 0.f, s10 = 0.f, s11 = 0.f;
    int iy = 2 * ph, ix = 2 * pw;
    #pragma unroll
    for (int ci = 0; ci < 3; ci++) {
        const float* xp = x + (((size_t)(n * 3 + ci) * 720 + iy) * 720 + ix);
        float a[4][4];
        #pragma unroll
        for (int r = 0; r < 4; r++)
            #pragma unroll
            for (int cc = 0; cc < 4; cc++)
                a[r][cc] = xp[r * 720 + cc];
        const float* wk = wp + ci * 9;
        #pragma unroll
        for (int kh = 0; kh < 3; kh++)
            #pragma unroll
            for (int kw = 0; kw < 3; kw++) {
                float wv = wk[kh * 3 + kw];
                s00 = fmaf(a[kh    ][kw    ], wv, s00);
                s01 = fmaf(a[kh    ][kw + 1], wv, s01);
                s10 = fmaf(a[kh + 1][kw    ], wv, s10);
                s11 = fmaf(a[kh + 1][kw + 1], wv, s11);
            }
    }
    float b = ws[B1R_OFF + c], al = a1[c];
    s00 += b; s01 += b; s10 += b; s11 += b;
    s00 = s00 >= 0.f ? s00 : al * s00;
    s01 = s01 >= 0.f ? s01 : al * s01;
    s10 = s10 >= 0.f ? s10 : al * s10;
    s11 = s11 >= 0.f ? s11 : al * s11;
    float m = fmaxf(fmaxf(s00, s01), fmaxf(s10, s11));
    pooled[((size_t)z * PH + ph) * PH + pw] = m;
}

// ---------------------------------------------------------------------------
// Stage 2: conv2 3x3 (10->16) + bias + PReLU.
// One thread per spatial position, all 16 output channels in registers.
// 90 input loads -> 1440 FMA (16:1).
// grid: (ceil(357/128), 357, 16), block 128
// ---------------------------------------------------------------------------
__global__ void conv2_kernel(const float* __restrict__ pooled,
                             const float* __restrict__ ws,
                             const float* __restrict__ b2,
                             const float* __restrict__ a2,
                             float* __restrict__ c2o) {
    int ow = blockIdx.x * blockDim.x + threadIdx.x;
    int oh = blockIdx.y;
    int n  = blockIdx.z;
    if (ow >= H2) return;
    const float* w2r = ws + W2R_OFF;
    float acc[16];
    #pragma unroll
    for (int co = 0; co < 16; co++) acc[co] = 0.f;
    for (int ci = 0; ci < 10; ci++) {
        const float* ip = pooled + (((size_t)(n * 10 + ci) * PH + oh) * PH + ow);
        #pragma unroll
        for (int kh = 0; kh < 3; kh++)
            #pragma unroll
            for (int kw = 0; kw < 3; kw++) {
                float v = ip[kh * PH + kw];
                const float* wp = w2r + ((ci * 3 + kh) * 3 + kw) * 16;
                #pragma unroll
                for (int co = 0; co < 16; co++) acc[co] = fmaf(v, wp[co], acc[co]);
            }
    }
    #pragma unroll
    for (int co = 0; co < 16; co++) {
        float v = acc[co] + b2[co];
        v = v >= 0.f ? v : a2[co] * v;
        c2o[(((size_t)(n * 16 + co) * H2 + oh) * H2 + ow)] = v;
    }
}

// ---------------------------------------------------------------------------
// Stage 3: conv3 3x3 (16->32) + bias + PReLU, fused with the two 1x1 heads
// (conv41 2-ch + softmax, conv42 4-ch). One thread per spatial position,
// all 32 conv3 channels in registers; 258 MB conv3 buffer never exists.
// grid: (ceil(355/128), 355, 16), block 128
// ---------------------------------------------------------------------------
__global__ void conv3_heads_kernel(const float* __restrict__ c2o,
                                   const float* __restrict__ ws,
                                   const float* __restrict__ b3,
                                   const float* __restrict__ a3,
                                   const float* __restrict__ w41,
                                   const float* __restrict__ b41,
                                   const float* __restrict__ w42,
                                   const float* __restrict__ b42,
                                   float* __restrict__ out) {
    int ow = blockIdx.x * blockDim.x + threadIdx.x;
    int oh = blockIdx.y;
    int n  = blockIdx.z;
    if (ow >= H3) return;
    const float* w3r = ws + W3R_OFF;
    float acc[32];
    #pragma unroll
    for (int co = 0; co < 32; co++) acc[co] = 0.f;
    for (int ci = 0; ci < 16; ci++) {
        const float* ip = c2o + (((size_t)(n * 16 + ci) * H2 + oh) * H2 + ow);
        #pragma unroll
        for (int kh = 0; kh < 3; kh++)
            #pragma unroll
            for (int kw = 0; kw < 3; kw++) {
                float v = ip[kh * H2 + kw];
                const float* wp = w3r + ((ci * 3 + kh) * 3 + kw) * 32;
                #pragma unroll
                for (int co = 0; co < 32; co++) acc[co] = fmaf(v, wp[co], acc[co]);
            }
    }
    float l0 = b41[0], l1 = b41[1];
    float r0 = b42[0], r1 = b42[1], r2 = b42[2], r3 = b42[3];
    #pragma unroll
    for (int c = 0; c < 32; c++) {
        float hv = acc[c] + b3[c];
        hv = hv >= 0.f ? hv : a3[c] * hv;
        l0 = fmaf(hv, w41[c],      l0);
        l1 = fmaf(hv, w41[32 + c], l1);
        r0 = fmaf(hv, w42[c],      r0);
        r1 = fmaf(hv, w42[32 + c], r1);
        r2 = fmaf(hv, w42[64 + c], r2);
        r3 = fmaf(hv, w42[96 + c], r3);
    }
    // softmax over the 2 logits
    float m  = fmaxf(l0, l1);
    float e0 = __expf(l0 - m), e1 = __expf(l1 - m);
    float inv = 1.0f / (e0 + e1);

    const size_t sp  = (size_t)H3 * H3;     // 126025
    size_t pos = (size_t)oh * H3 + ow;
    float* reg  = out;                       // [16,4,355,355]
    float* prob = out + (size_t)16 * 4 * sp; // [16,2,355,355]
    reg[((size_t)(n * 4 + 0)) * sp + pos] = r0;
    reg[((size_t)(n * 4 + 1)) * sp + pos] = r1;
    reg[((size_t)(n * 4 + 2)) * sp + pos] = r2;
    reg[((size_t)(n * 4 + 3)) * sp + pos] = r3;
    prob[((size_t)(n * 2 + 0)) * sp + pos] = e0 * inv;
    prob[((size_t)(n * 2 + 1)) * sp + pos] = e1 * inv;
}

extern "C" void kernel_launch(void* const* d_in, const int* in_sizes, int n_in,
                              void* d_out, int out_size, void* d_ws, size_t ws_size,
                              hipStream_t stream) {
    const float* x   = (const float*)d_in[0];
    const float* w1  = (const float*)d_in[1];
    const float* b1  = (const float*)d_in[2];
    const float* a1  = (const float*)d_in[3];
    const float* w2  = (const float*)d_in[4];
    const float* b2  = (const float*)d_in[5];
    const float* a2  = (const float*)d_in[6];
    const float* w3  = (const float*)d_in[7];
    const float* b3  = (const float*)d_in[8];
    const float* a3  = (const float*)d_in[9];
    const float* w41 = (const float*)d_in[10];
    const float* b41 = (const float*)d_in[11];
    const float* w42 = (const float*)d_in[12];
    const float* b42 = (const float*)d_in[13];
    float* out = (float*)d_out;
    float* ws  = (float*)d_ws;

    float* pooled = ws + POOL_OFF;   // [16,10,359,359]
    float* c2o    = ws + C2O_OFF;    // [16,16,357,357]

    repack_kernel<<<1, 256, 0, stream>>>(w1, b1, w2, w3, ws);

    {
        dim3 grid((PH + 127) / 128, PH, 16 * 10);
        conv1_pool_kernel<<<grid, 128, 0, stream>>>(x, ws, a1, pooled);
    }
    {
        dim3 grid((H2 + 127) / 128, H2, 16);
        conv2_kernel<<<grid, 128, 0, stream>>>(pooled, ws, b2, a2, c2o);
    }
    {
        dim3 grid((H3 + 127) / 128, H3, 16);
        conv3_heads_kernel<<<grid, 128, 0, stream>>>(c2o, ws, b3, a3,
                                                     w41, b41, w42, b42, out);
    }
}

// Round 2
// 507.260 us; speedup vs baseline: 1.5054x; 1.5054x over previous
//
#include <hip/hip_runtime.h>
#include <cstddef>

// ---------------------------------------------------------------------------
// MTCNN P-Net forward, fp32, NCHW.
//   x[16,3,720,720] -> norm -> conv1(3->10,3x3)+PReLU -> maxpool2
//     -> conv2(10->16,3x3)+PReLU -> conv3(16->32,3x3)+PReLU
//     -> {conv41(32->2,1x1)+softmax, conv42(32->4,1x1)}
//   out = concat(reg[16,4,355,355], prob[16,2,355,355]) flat fp32
// ---------------------------------------------------------------------------

#define H1 718   // conv1 out spatial (720-2)
#define PH 359   // pooled spatial (718/2)
#define H2 357   // conv2 out spatial (359-2)
#define H3 355   // conv3 out spatial (357-2)

// workspace layout (float offsets)
#define W1R_OFF 0              // 270  (10*3*3*3), pre-scaled by 1/128
#define B1R_OFF 288            // 10   (norm folded in)
#define W2R_OFF 320            // 1440 (reordered [k][co], k=ci*9+kh*3+kw)
#define W3R_OFF 1792           // 4608 (reordered [k][co])
#define POOL_OFF 6400          // 16*10*359*359 = 20620960
#define C2O_OFF (POOL_OFF + (size_t)16*10*PH*PH)   // 16*16*357*357 = 32626944

// ---------------------------------------------------------------------------
// Weight repack: fold input normalization into conv1, transpose conv2/conv3
// weights to k-major / c_out-minor so the per-(ci,kh,kw) weight vector is a
// contiguous (wave-uniform) 16/32-float block.
// ---------------------------------------------------------------------------
__global__ void repack_kernel(const float* __restrict__ w1, const float* __restrict__ b1,
                              const float* __restrict__ w2, const float* __restrict__ w3,
                              float* __restrict__ ws) {
    int t = threadIdx.x;
    float* w1r = ws + W1R_OFF;
    float* b1r = ws + B1R_OFF;
    float* w2r = ws + W2R_OFF;
    float* w3r = ws + W3R_OFF;
    const float S = 0.0078125f;   // 1/128
    // conv1 weights scaled: conv((x-127.5)*S, w) == conv(x, S*w) - 127.5*S*sum(w)
    for (int i = t; i < 270; i += blockDim.x) w1r[i] = w1[i] * S;
    if (t < 10) {
        float s = 0.f;
        for (int i = 0; i < 27; i++) s += w1[t * 27 + i];
        b1r[t] = b1[t] - 127.5f * S * s;
    }
    // w2: [16,10,3,3] -> w2r[k*16+co], k = ci*9+kh*3+kw
    for (int i = t; i < 1440; i += blockDim.x) {
        int co = i & 15, k = i >> 4;
        w2r[i] = w2[co * 90 + k];
    }
    // w3: [32,16,3,3] -> w3r[k*32+co], k = ci*9+kh*3+kw
    for (int i = t; i < 4608; i += blockDim.x) {
        int co = i & 31, k = i >> 5;
        w3r[i] = w3[co * 144 + k];
    }
}

// ---------------------------------------------------------------------------
// Stage 1: (normalized) conv1 3x3 + bias + PReLU + maxpool 2x2, fused.
// R2 restructure: ONE thread computes ALL 10 output channels for its pooled
// pixel (was: grid.z carried the channel -> 10x re-read of x, 540 MB HBM
// fetch, 19% VALUBusy). Input window (4x4x3, 48 floats) is read exactly once
// via coalesced float2 loads (lane i covers floats [2i,2i+4) -> contiguous
// 512 B wave segment); weights are wave-uniform scalar loads.
// 48 loads -> 1080 FMA per thread. 40 accumulators, ~80 VGPR.
// grid: (ceil(359/128), 359, 16), block 128
// ---------------------------------------------------------------------------
__global__ void conv1_pool_kernel(const float* __restrict__ x,
                                  const float* __restrict__ ws,
                                  const float* __restrict__ a1,
                                  float* __restrict__ pooled) {
    int pw = blockIdx.x * blockDim.x + threadIdx.x;
    int ph = blockIdx.y;
    int n  = blockIdx.z;
    if (pw >= PH) return;
    int iy = 2 * ph, ix = 2 * pw;

    float acc[10][4];
    #pragma unroll
    for (int c = 0; c < 10; c++)
        #pragma unroll
        for (int p = 0; p < 4; p++) acc[c][p] = 0.f;

    #pragma unroll
    for (int ci = 0; ci < 3; ci++) {
        const float* xp = x + (((size_t)(n * 3 + ci) * 720 + iy) * 720 + ix);
        float win[4][4];
        #pragma unroll
        for (int r = 0; r < 4; r++) {
            float2 v0 = *(const float2*)(xp + r * 720);
            float2 v1 = *(const float2*)(xp + r * 720 + 2);
            win[r][0] = v0.x; win[r][1] = v0.y; win[r][2] = v1.x; win[r][3] = v1.y;
        }
        #pragma unroll
        for (int c = 0; c < 10; c++) {
            const float* wk = ws + W1R_OFF + c * 27 + ci * 9;   // wave-uniform
            #pragma unroll
            for (int kh = 0; kh < 3; kh++)
                #pragma unroll
                for (int kw = 0; kw < 3; kw++) {
                    float wv = wk[kh * 3 + kw];
                    acc[c][0] = fmaf(win[kh    ][kw    ], wv, acc[c][0]);
                    acc[c][1] = fmaf(win[kh    ][kw + 1], wv, acc[c][1]);
                    acc[c][2] = fmaf(win[kh + 1][kw    ], wv, acc[c][2]);
                    acc[c][3] = fmaf(win[kh + 1][kw + 1], wv, acc[c][3]);
                }
        }
    }

    size_t base = ((size_t)(n * 10) * PH + ph) * PH + pw;
    const size_t cstride = (size_t)PH * PH;
    #pragma unroll
    for (int c = 0; c < 10; c++) {
        float b = ws[B1R_OFF + c], al = a1[c];
        float s0 = acc[c][0] + b, s1 = acc[c][1] + b;
        float s2 = acc[c][2] + b, s3 = acc[c][3] + b;
        s0 = s0 >= 0.f ? s0 : al * s0;
        s1 = s1 >= 0.f ? s1 : al * s1;
        s2 = s2 >= 0.f ? s2 : al * s2;
        s3 = s3 >= 0.f ? s3 : al * s3;
        pooled[base + c * cstride] = fmaxf(fmaxf(s0, s1), fmaxf(s2, s3));
    }
}

// ---------------------------------------------------------------------------
// Stage 2: conv2 3x3 (10->16) + bias + PReLU.
// One thread per spatial position, all 16 output channels in registers.
// 90 input loads -> 1440 FMA (16:1).
// grid: (ceil(357/128), 357, 16), block 128
// ---------------------------------------------------------------------------
__global__ void conv2_kernel(const float* __restrict__ pooled,
                             const float* __restrict__ ws,
                             const float* __restrict__ b2,
                             const float* __restrict__ a2,
                             float* __restrict__ c2o) {
    int ow = blockIdx.x * blockDim.x + threadIdx.x;
    int oh = blockIdx.y;
    int n  = blockIdx.z;
    if (ow >= H2) return;
    const float* w2r = ws + W2R_OFF;
    float acc[16];
    #pragma unroll
    for (int co = 0; co < 16; co++) acc[co] = 0.f;
    for (int ci = 0; ci < 10; ci++) {
        const float* ip = pooled + (((size_t)(n * 10 + ci) * PH + oh) * PH + ow);
        #pragma unroll
        for (int kh = 0; kh < 3; kh++)
            #pragma unroll
            for (int kw = 0; kw < 3; kw++) {
                float v = ip[kh * PH + kw];
                const float* wp = w2r + ((ci * 3 + kh) * 3 + kw) * 16;
                #pragma unroll
                for (int co = 0; co < 16; co++) acc[co] = fmaf(v, wp[co], acc[co]);
            }
    }
    #pragma unroll
    for (int co = 0; co < 16; co++) {
        float v = acc[co] + b2[co];
        v = v >= 0.f ? v : a2[co] * v;
        c2o[(((size_t)(n * 16 + co) * H2 + oh) * H2 + ow)] = v;
    }
}

// ---------------------------------------------------------------------------
// Stage 3: conv3 3x3 (16->32) + bias + PReLU, fused with the two 1x1 heads
// (conv41 2-ch + softmax, conv42 4-ch). One thread per spatial position,
// all 32 conv3 channels in registers; 258 MB conv3 buffer never exists.
// grid: (ceil(355/128), 355, 16), block 128
// ---------------------------------------------------------------------------
__global__ void conv3_heads_kernel(const float* __restrict__ c2o,
                                   const float* __restrict__ ws,
                                   const float* __restrict__ b3,
                                   const float* __restrict__ a3,
                                   const float* __restrict__ w41,
                                   const float* __restrict__ b41,
                                   const float* __restrict__ w42,
                                   const float* __restrict__ b42,
                                   float* __restrict__ out) {
    int ow = blockIdx.x * blockDim.x + threadIdx.x;
    int oh = blockIdx.y;
    int n  = blockIdx.z;
    if (ow >= H3) return;
    const float* w3r = ws + W3R_OFF;
    float acc[32];
    #pragma unroll
    for (int co = 0; co < 32; co++) acc[co] = 0.f;
    for (int ci = 0; ci < 16; ci++) {
        const float* ip = c2o + (((size_t)(n * 16 + ci) * H2 + oh) * H2 + ow);
        #pragma unroll
        for (int kh = 0; kh < 3; kh++)
            #pragma unroll
            for (int kw = 0; kw < 3; kw++) {
                float v = ip[kh * H2 + kw];
                const float* wp = w3r + ((ci * 3 + kh) * 3 + kw) * 32;
                #pragma unroll
                for (int co = 0; co < 32; co++) acc[co] = fmaf(v, wp[co], acc[co]);
            }
    }
    float l0 = b41[0], l1 = b41[1];
    float r0 = b42[0], r1 = b42[1], r2 = b42[2], r3 = b42[3];
    #pragma unroll
    for (int c = 0; c < 32; c++) {
        float hv = acc[c] + b3[c];
        hv = hv >= 0.f ? hv : a3[c] * hv;
        l0 = fmaf(hv, w41[c],      l0);
        l1 = fmaf(hv, w41[32 + c], l1);
        r0 = fmaf(hv, w42[c],      r0);
        r1 = fmaf(hv, w42[32 + c], r1);
        r2 = fmaf(hv, w42[64 + c], r2);
        r3 = fmaf(hv, w42[96 + c], r3);
    }
    // softmax over the 2 logits
    float m  = fmaxf(l0, l1);
    float e0 = __expf(l0 - m), e1 = __expf(l1 - m);
    float inv = 1.0f / (e0 + e1);

    const size_t sp  = (size_t)H3 * H3;     // 126025
    size_t pos = (size_t)oh * H3 + ow;
    float* reg  = out;                       // [16,4,355,355]
    float* prob = out + (size_t)16 * 4 * sp; // [16,2,355,355]
    reg[((size_t)(n * 4 + 0)) * sp + pos] = r0;
    reg[((size_t)(n * 4 + 1)) * sp + pos] = r1;
    reg[((size_t)(n * 4 + 2)) * sp + pos] = r2;
    reg[((size_t)(n * 4 + 3)) * sp + pos] = r3;
    prob[((size_t)(n * 2 + 0)) * sp + pos] = e0 * inv;
    prob[((size_t)(n * 2 + 1)) * sp + pos] = e1 * inv;
}

extern "C" void kernel_launch(void* const* d_in, const int* in_sizes, int n_in,
                              void* d_out, int out_size, void* d_ws, size_t ws_size,
                              hipStream_t stream) {
    const float* x   = (const float*)d_in[0];
    const float* w1  = (const float*)d_in[1];
    const float* b1  = (const float*)d_in[2];
    const float* a1  = (const float*)d_in[3];
    const float* w2  = (const float*)d_in[4];
    const float* b2  = (const float*)d_in[5];
    const float* a2  = (const float*)d_in[6];
    const float* w3  = (const float*)d_in[7];
    const float* b3  = (const float*)d_in[8];
    const float* a3  = (const float*)d_in[9];
    const float* w41 = (const float*)d_in[10];
    const float* b41 = (const float*)d_in[11];
    const float* w42 = (const float*)d_in[12];
    const float* b42 = (const float*)d_in[13];
    float* out = (float*)d_out;
    float* ws  = (float*)d_ws;

    float* pooled = ws + POOL_OFF;   // [16,10,359,359]
    float* c2o    = ws + C2O_OFF;    // [16,16,357,357]

    repack_kernel<<<1, 256, 0, stream>>>(w1, b1, w2, w3, ws);

    {
        dim3 grid((PH + 127) / 128, PH, 16);
        conv1_pool_kernel<<<grid, 128, 0, stream>>>(x, ws, a1, pooled);
    }
    {
        dim3 grid((H2 + 127) / 128, H2, 16);
        conv2_kernel<<<grid, 128, 0, stream>>>(pooled, ws, b2, a2, c2o);
    }
    {
        dim3 grid((H3 + 127) / 128, H3, 16);
        conv3_heads_kernel<<<grid, 128, 0, stream>>>(c2o, ws, b3, a3,
                                                     w41, b41, w42, b42, out);
    }
}

// Round 3
// 346.912 us; speedup vs baseline: 2.2012x; 1.4622x over previous
//
#include <hip/hip_runtime.h>
#include <hip/hip_bf16.h>
#include <cstddef>

// ---------------------------------------------------------------------------
// MTCNN P-Net forward, NCHW in/out.
//   x[16,3,720,720] -> norm -> conv1(3->10,3x3)+PReLU -> maxpool2   (fp32)
//     -> conv2(10->16,3x3)+PReLU  -> NHWC bf16
//     -> conv3(16->32,3x3)+PReLU via MFMA 32x32x16 bf16, fused heads
//   out = concat(reg[16,4,355,355], prob[16,2,355,355]) flat fp32
// ---------------------------------------------------------------------------

#define H1 718
#define PH 359   // pooled spatial
#define H2 357   // conv2 out spatial
#define H3 355   // conv3 out spatial

// workspace layout (float offsets)
#define W1R_OFF 0              // 270 fp32, pre-scaled by 1/128
#define B1R_OFF 288            // 10 fp32 (norm folded in)
#define W2R_OFF 320            // 1440 fp32 [k][co], k=ci*9+kh*3+kw
#define BW3_OFF 1792           // 4608 bf16 = 2304 floats: MFMA B-frags [tap][lane][8]
#define POOL_OFF 6400          // fp32 [16,10,359,359]
#define C2H_OFF (POOL_OFF + (size_t)16*10*PH*PH)   // bf16 NHWC [16,357,357,16]
// C2H_OFF*4 = 82509440 B, 32B-aligned.

typedef short bf16x8 __attribute__((ext_vector_type(8)));   // 8 bf16 (guide §3 frag type)
typedef float f32x16 __attribute__((ext_vector_type(16)));

// ---------------------------------------------------------------------------
// Weight repack.
//  - conv1: fold (x-127.5)/128 into weights/bias.
//  - conv2: [16,10,3,3] -> [k][co] fp32.
//  - conv3: [32,16,3,3] -> MFMA 32x32x16 B-frag order, bf16:
//      frag[tap][lane][j] = w3[co=lane&31][ci=(lane>>5)*8+j][kh=tap/3][kw=tap%3]
// ---------------------------------------------------------------------------
__global__ void repack_kernel(const float* __restrict__ w1, const float* __restrict__ b1,
                              const float* __restrict__ w2, const float* __restrict__ w3,
                              float* __restrict__ ws) {
    int t = threadIdx.x;
    const float S = 0.0078125f;
    for (int i = t; i < 270; i += blockDim.x) ws[W1R_OFF + i] = w1[i] * S;
    if (t < 10) {
        float s = 0.f;
        for (int i = 0; i < 27; i++) s += w1[t * 27 + i];
        ws[B1R_OFF + t] = b1[t] - 127.5f * S * s;
    }
    for (int i = t; i < 1440; i += blockDim.x) {
        int co = i & 15, k = i >> 4;
        ws[W2R_OFF + i] = w2[co * 90 + k];
    }
    unsigned short* bw3 = (unsigned short*)(ws + BW3_OFF);
    for (int e = t; e < 4608; e += blockDim.x) {
        int tap = e >> 9;            // 0..8
        int rem = e & 511;
        int l = rem >> 3, j = rem & 7;
        int kh = tap / 3, kw = tap % 3;
        int co = l & 31, ci = ((l >> 5) << 3) + j;
        float v = w3[co * 144 + ci * 9 + kh * 3 + kw];
        __hip_bfloat16 h = __float2bfloat16(v);
        bw3[e] = *(unsigned short*)&h;
    }
}

// ---------------------------------------------------------------------------
// Stage 1: norm+conv1+PReLU+maxpool fused, all 10 channels per thread. fp32.
// ---------------------------------------------------------------------------
__global__ void conv1_pool_kernel(const float* __restrict__ x,
                                  const float* __restrict__ ws,
                                  const float* __restrict__ a1,
                                  float* __restrict__ pooled) {
    int pw = blockIdx.x * blockDim.x + threadIdx.x;
    int ph = blockIdx.y;
    int n  = blockIdx.z;
    if (pw >= PH) return;
    int iy = 2 * ph, ix = 2 * pw;

    float acc[10][4];
    #pragma unroll
    for (int c = 0; c < 10; c++)
        #pragma unroll
        for (int p = 0; p < 4; p++) acc[c][p] = 0.f;

    #pragma unroll
    for (int ci = 0; ci < 3; ci++) {
        const float* xp = x + (((size_t)(n * 3 + ci) * 720 + iy) * 720 + ix);
        float win[4][4];
        #pragma unroll
        for (int r = 0; r < 4; r++) {
            float2 v0 = *(const float2*)(xp + r * 720);
            float2 v1 = *(const float2*)(xp + r * 720 + 2);
            win[r][0] = v0.x; win[r][1] = v0.y; win[r][2] = v1.x; win[r][3] = v1.y;
        }
        #pragma unroll
        for (int c = 0; c < 10; c++) {
            const float* wk = ws + W1R_OFF + c * 27 + ci * 9;
            #pragma unroll
            for (int kh = 0; kh < 3; kh++)
                #pragma unroll
                for (int kw = 0; kw < 3; kw++) {
                    float wv = wk[kh * 3 + kw];
                    acc[c][0] = fmaf(win[kh    ][kw    ], wv, acc[c][0]);
                    acc[c][1] = fmaf(win[kh    ][kw + 1], wv, acc[c][1]);
                    acc[c][2] = fmaf(win[kh + 1][kw    ], wv, acc[c][2]);
                    acc[c][3] = fmaf(win[kh + 1][kw + 1], wv, acc[c][3]);
                }
        }
    }

    size_t base = ((size_t)(n * 10) * PH + ph) * PH + pw;
    const size_t cstride = (size_t)PH * PH;
    #pragma unroll
    for (int c = 0; c < 10; c++) {
        float b = ws[B1R_OFF + c], al = a1[c];
        float s0 = acc[c][0] + b, s1 = acc[c][1] + b;
        float s2 = acc[c][2] + b, s3 = acc[c][3] + b;
        s0 = s0 >= 0.f ? s0 : al * s0;
        s1 = s1 >= 0.f ? s1 : al * s1;
        s2 = s2 >= 0.f ? s2 : al * s2;
        s3 = s3 >= 0.f ? s3 : al * s3;
        pooled[base + c * cstride] = fmaxf(fmaxf(s0, s1), fmaxf(s2, s3));
    }
}

// ---------------------------------------------------------------------------
// Stage 2: conv2 3x3 (10->16) + bias + PReLU -> NHWC bf16 (feeds MFMA conv3).
// Thread writes its pixel's 16 channels as one 32 B contiguous chunk.
// ---------------------------------------------------------------------------
__global__ void conv2_kernel(const float* __restrict__ pooled,
                             const float* __restrict__ ws,
                             const float* __restrict__ b2,
                             const float* __restrict__ a2,
                             __hip_bfloat16* __restrict__ c2h) {
    int ow = blockIdx.x * blockDim.x + threadIdx.x;
    int oh = blockIdx.y;
    int n  = blockIdx.z;
    if (ow >= H2) return;
    const float* w2r = ws + W2R_OFF;
    float acc[16];
    #pragma unroll
    for (int co = 0; co < 16; co++) acc[co] = 0.f;
    for (int ci = 0; ci < 10; ci++) {
        const float* ip = pooled + (((size_t)(n * 10 + ci) * PH + oh) * PH + ow);
        #pragma unroll
        for (int kh = 0; kh < 3; kh++)
            #pragma unroll
            for (int kw = 0; kw < 3; kw++) {
                float v = ip[kh * PH + kw];
                const float* wp = w2r + ((ci * 3 + kh) * 3 + kw) * 16;
                #pragma unroll
                for (int co = 0; co < 16; co++) acc[co] = fmaf(v, wp[co], acc[co]);
            }
    }
    __hip_bfloat16 tmp[16];
    #pragma unroll
    for (int co = 0; co < 16; co++) {
        float v = acc[co] + b2[co];
        v = v >= 0.f ? v : a2[co] * v;
        tmp[co] = __float2bfloat16(v);
    }
    float4* dst = (float4*)(c2h + (((size_t)(n * H2 + oh) * H2 + ow) << 4));
    dst[0] = ((float4*)tmp)[0];
    dst[1] = ((float4*)tmp)[1];
}

// ---------------------------------------------------------------------------
// Stage 3: conv3 3x3 (16->32) + PReLU + heads, MFMA 32x32x16 bf16.
// Implicit GEMM: M=32 pixel columns, N=32 c_out, K=16 c_in; 9 taps = 9 K-steps
// (no padding). Wave = 2 output rows x 32 cols; workgroup = 4 waves = 8 rows.
// A-frag: lane l reads pixel (ow0 + (l&31) + kw) row (oh+kh), channels
// (l>>5)*8..+8 -> one contiguous 16 B NHWC load. B-frags register-resident.
// C/D layout (m101): col(c_out)=lane&31, row(pixel)=(r&3)+8*(r>>2)+4*(l>>5).
// Heads via LDS round-trip (stride 33 -> conflict-free), then softmax.
// Edges: clamped loads (valid pixels never clamp), masked stores.
// grid: (ceil(355/32)=12, ceil(355/8)=45, 16), block 256
// ---------------------------------------------------------------------------
__global__ __launch_bounds__(256, 1)
void conv3_heads_kernel(const __hip_bfloat16* __restrict__ c2h,
                        const float* __restrict__ ws,
                        const float* __restrict__ b3,
                        const float* __restrict__ a3,
                        const float* __restrict__ w41,
                        const float* __restrict__ b41,
                        const float* __restrict__ w42,
                        const float* __restrict__ b42,
                        float* __restrict__ out) {
    int wv = threadIdx.x >> 6;
    int l  = threadIdx.x & 63;
    int ow0 = blockIdx.x * 32;
    int oh0 = blockIdx.y * 8 + wv * 2;
    int n   = blockIdx.z;

    int m    = l & 31;        // A: pixel col offset; D: c_out channel
    int half = l >> 5;
    int choff = half << 3;

    // preload 9 B-frags (36 VGPRs)
    const bf16x8* bw = (const bf16x8*)(ws + BW3_OFF);
    bf16x8 bfr[9];
    #pragma unroll
    for (int t = 0; t < 9; t++) bfr[t] = bw[t * 64 + l];

    f32x16 acc0, acc1;
    #pragma unroll
    for (int i = 0; i < 16; i++) { acc0[i] = 0.f; acc1[i] = 0.f; }

    #pragma unroll
    for (int kh = 0; kh < 3; kh++) {
        int ih0 = oh0 + kh;     if (ih0 > H2 - 1) ih0 = H2 - 1;
        int ih1 = oh0 + 1 + kh; if (ih1 > H2 - 1) ih1 = H2 - 1;
        #pragma unroll
        for (int kw = 0; kw < 3; kw++) {
            int iw = ow0 + m + kw; if (iw > H2 - 1) iw = H2 - 1;
            const bf16x8* a0p = (const bf16x8*)(c2h + ((((size_t)n * H2 + ih0) * H2 + iw) << 4) + choff);
            const bf16x8* a1p = (const bf16x8*)(c2h + ((((size_t)n * H2 + ih1) * H2 + iw) << 4) + choff);
            bf16x8 a0 = *a0p;
            bf16x8 a1 = *a1p;
            int tap = kh * 3 + kw;
            acc0 = __builtin_amdgcn_mfma_f32_32x32x16_bf16(a0, bfr[tap], acc0, 0, 0, 0);
            acc1 = __builtin_amdgcn_mfma_f32_32x32x16_bf16(a1, bfr[tap], acc1, 0, 0, 0);
        }
    }

    // bias + PReLU, stash h to LDS (pixel-major, stride 33 = conflict-free)
    __shared__ float hbuf[4][64 * 33];
    float* hb = hbuf[wv];
    float bb = b3[m], aa = a3[m];           // ch = m for this lane
    #pragma unroll
    for (int t = 0; t < 2; t++) {
        #pragma unroll
        for (int r = 0; r < 16; r++) {
            int mprime = (r & 3) + ((r >> 2) << 3) + (half << 2);  // pixel col 0..31
            float v = (t ? acc1[r] : acc0[r]) + bb;
            v = v >= 0.f ? v : aa * v;
            hb[(t * 32 + mprime) * 33 + m] = v;
        }
    }
    __syncthreads();

    // heads: lane l handles pixel l (row = oh0 + (l>>5), col = ow0 + (l&31))
    int poh = oh0 + (l >> 5);
    int pow_ = ow0 + (l & 31);
    float h[32];
    #pragma unroll
    for (int c = 0; c < 32; c++) h[c] = hb[l * 33 + c];

    float l0 = b41[0], l1 = b41[1];
    float r0 = b42[0], r1 = b42[1], r2 = b42[2], r3 = b42[3];
    #pragma unroll
    for (int c = 0; c < 32; c++) {
        float hv = h[c];
        l0 = fmaf(hv, w41[c],      l0);
        l1 = fmaf(hv, w41[32 + c], l1);
        r0 = fmaf(hv, w42[c],      r0);
        r1 = fmaf(hv, w42[32 + c], r1);
        r2 = fmaf(hv, w42[64 + c], r2);
        r3 = fmaf(hv, w42[96 + c], r3);
    }
    float mx  = fmaxf(l0, l1);
    float e0 = __expf(l0 - mx), e1 = __expf(l1 - mx);
    float inv = 1.0f / (e0 + e1);

    if (poh < H3 && pow_ < H3) {
        const size_t sp = (size_t)H3 * H3;
        size_t pos = (size_t)poh * H3 + pow_;
        float* reg  = out;
        float* prob = out + (size_t)16 * 4 * sp;
        reg[((size_t)(n * 4 + 0)) * sp + pos] = r0;
        reg[((size_t)(n * 4 + 1)) * sp + pos] = r1;
        reg[((size_t)(n * 4 + 2)) * sp + pos] = r2;
        reg[((size_t)(n * 4 + 3)) * sp + pos] = r3;
        prob[((size_t)(n * 2 + 0)) * sp + pos] = e0 * inv;
        prob[((size_t)(n * 2 + 1)) * sp + pos] = e1 * inv;
    }
}

extern "C" void kernel_launch(void* const* d_in, const int* in_sizes, int n_in,
                              void* d_out, int out_size, void* d_ws, size_t ws_size,
                              hipStream_t stream) {
    const float* x   = (const float*)d_in[0];
    const float* w1  = (const float*)d_in[1];
    const float* b1  = (const float*)d_in[2];
    const float* a1  = (const float*)d_in[3];
    const float* w2  = (const float*)d_in[4];
    const float* b2  = (const float*)d_in[5];
    const float* a2  = (const float*)d_in[6];
    const float* w3  = (const float*)d_in[7];
    const float* b3  = (const float*)d_in[8];
    const float* a3  = (const float*)d_in[9];
    const float* w41 = (const float*)d_in[10];
    const float* b41 = (const float*)d_in[11];
    const float* w42 = (const float*)d_in[12];
    const float* b42 = (const float*)d_in[13];
    float* out = (float*)d_out;
    float* ws  = (float*)d_ws;

    float* pooled        = ws + POOL_OFF;
    __hip_bfloat16* c2h  = (__hip_bfloat16*)(ws + C2H_OFF);

    repack_kernel<<<1, 256, 0, stream>>>(w1, b1, w2, w3, ws);

    {
        dim3 grid((PH + 127) / 128, PH, 16);
        conv1_pool_kernel<<<grid, 128, 0, stream>>>(x, ws, a1, pooled);
    }
    {
        dim3 grid((H2 + 127) / 128, H2, 16);
        conv2_kernel<<<grid, 128, 0, stream>>>(pooled, ws, b2, a2, c2h);
    }
    {
        dim3 grid((H3 + 31) / 32, (H3 + 7) / 8, 16);
        conv3_heads_kernel<<<grid, 256, 0, stream>>>(c2h, ws, b3, a3,
                                                     w41, b41, w42, b42, out);
    }
}

// Round 4
// 316.586 us; speedup vs baseline: 2.4120x; 1.0958x over previous
//
#include <hip/hip_runtime.h>
#include <hip/hip_bf16.h>
#include <cstddef>

// ---------------------------------------------------------------------------
// MTCNN P-Net forward, NCHW in/out.
//   x[16,3,720,720] -> norm -> conv1(3->10,3x3)+PReLU -> maxpool2 (fp32 math)
//     -> pooled NHWC bf16 (padded 10->16 ch)
//     -> conv2(16->16,3x3) via MFMA 16x16x32 bf16 -> NHWC bf16
//     -> conv3(16->32,3x3)+PReLU via MFMA 32x32x16 bf16, fused heads
//   out = concat(reg[16,4,355,355], prob[16,2,355,355]) flat fp32
// ---------------------------------------------------------------------------

#define H1 718
#define PH 359   // pooled spatial
#define H2 357   // conv2 out spatial
#define H3 355   // conv3 out spatial

// workspace layout (float offsets)
#define W1R_OFF 0              // 270 fp32, pre-scaled by 1/128
#define B1R_OFF 288            // 10 fp32 (norm folded in)
#define AW2_OFF 320            // 2560 bf16 = 1280 fl: conv2 A-frags [step][lane][8]
#define BW3_OFF 1600           // 4608 bf16 = 2304 fl: conv3 B-frags [tap][lane][8]
#define P16_OFF 4096           // pooled NHWC bf16 [16,359,359,16] = 16496768 fl
#define C2H_OFF 16500864       // conv2 out NHWC bf16 [16,357,357,16] = 16313472 fl

typedef short bf16x8 __attribute__((ext_vector_type(8)));
typedef float f32x4  __attribute__((ext_vector_type(4)));
typedef float f32x16 __attribute__((ext_vector_type(16)));
typedef unsigned short ushort4v __attribute__((ext_vector_type(4)));

// ---------------------------------------------------------------------------
// Weight repack.
//  - conv1: fold (x-127.5)/128 into weights/bias (fp32).
//  - conv2: -> MFMA 16x16x32 A-frag order (A = weights, M=c_out), bf16:
//      k in [0,32) of step s: tap = 2s + (k>=16), ci = k&15 (real if ci<10,tap<9)
//      afrag[s][lane][j]: m=lane&15=c_out, k=(lane>>4)*8+j
//  - conv3: -> MFMA 32x32x16 B-frag order, bf16 (as R3, verified).
// ---------------------------------------------------------------------------
__global__ void repack_kernel(const float* __restrict__ w1, const float* __restrict__ b1,
                              const float* __restrict__ w2, const float* __restrict__ w3,
                              float* __restrict__ ws) {
    int t = threadIdx.x;
    const float S = 0.0078125f;
    for (int i = t; i < 270; i += blockDim.x) ws[W1R_OFF + i] = w1[i] * S;
    if (t < 10) {
        float s = 0.f;
        for (int i = 0; i < 27; i++) s += w1[t * 27 + i];
        ws[B1R_OFF + t] = b1[t] - 127.5f * S * s;
    }
    unsigned short* aw2 = (unsigned short*)(ws + AW2_OFF);
    for (int e = t; e < 2560; e += blockDim.x) {
        int s = e >> 9;              // K-step 0..4
        int rem = e & 511;
        int l = rem >> 3, j = rem & 7;
        int q = l >> 4, co = l & 15;
        int tap = 2 * s + (q >> 1);
        int ci  = ((q & 1) << 3) + j;
        float v = (tap < 9 && ci < 10) ? w2[co * 90 + ci * 9 + tap] : 0.f;
        __hip_bfloat16 h = __float2bfloat16(v);
        aw2[e] = *(unsigned short*)&h;
    }
    unsigned short* bw3 = (unsigned short*)(ws + BW3_OFF);
    for (int e = t; e < 4608; e += blockDim.x) {
        int tap = e >> 9;
        int rem = e & 511;
        int l = rem >> 3, j = rem & 7;
        int kh = tap / 3, kw = tap % 3;
        int co = l & 31, ci = ((l >> 5) << 3) + j;
        float v = w3[co * 144 + ci * 9 + kh * 3 + kw];
        __hip_bfloat16 h = __float2bfloat16(v);
        bw3[e] = *(unsigned short*)&h;
    }
}

// ---------------------------------------------------------------------------
// Stage 1: norm+conv1+PReLU+maxpool fused, all 10 channels per thread.
// fp32 math; output NHWC bf16 padded to 16 ch (one 32 B store per thread,
// fully coalesced; feeds conv2's MFMA B-loads).
// ---------------------------------------------------------------------------
__global__ void conv1_pool_kernel(const float* __restrict__ x,
                                  const float* __restrict__ ws,
                                  const float* __restrict__ a1,
                                  __hip_bfloat16* __restrict__ p16) {
    int pw = blockIdx.x * blockDim.x + threadIdx.x;
    int ph = blockIdx.y;
    int n  = blockIdx.z;
    if (pw >= PH) return;
    int iy = 2 * ph, ix = 2 * pw;

    float acc[10][4];
    #pragma unroll
    for (int c = 0; c < 10; c++)
        #pragma unroll
        for (int p = 0; p < 4; p++) acc[c][p] = 0.f;

    #pragma unroll
    for (int ci = 0; ci < 3; ci++) {
        const float* xp = x + (((size_t)(n * 3 + ci) * 720 + iy) * 720 + ix);
        float win[4][4];
        #pragma unroll
        for (int r = 0; r < 4; r++) {
            float2 v0 = *(const float2*)(xp + r * 720);
            float2 v1 = *(const float2*)(xp + r * 720 + 2);
            win[r][0] = v0.x; win[r][1] = v0.y; win[r][2] = v1.x; win[r][3] = v1.y;
        }
        #pragma unroll
        for (int c = 0; c < 10; c++) {
            const float* wk = ws + W1R_OFF + c * 27 + ci * 9;
            #pragma unroll
            for (int kh = 0; kh < 3; kh++)
                #pragma unroll
                for (int kw = 0; kw < 3; kw++) {
                    float wv = wk[kh * 3 + kw];
                    acc[c][0] = fmaf(win[kh    ][kw    ], wv, acc[c][0]);
                    acc[c][1] = fmaf(win[kh    ][kw + 1], wv, acc[c][1]);
                    acc[c][2] = fmaf(win[kh + 1][kw    ], wv, acc[c][2]);
                    acc[c][3] = fmaf(win[kh + 1][kw + 1], wv, acc[c][3]);
                }
        }
    }

    __hip_bfloat16 o[16];
    #pragma unroll
    for (int c = 0; c < 10; c++) {
        float b = ws[B1R_OFF + c], al = a1[c];
        float s0 = acc[c][0] + b, s1 = acc[c][1] + b;
        float s2 = acc[c][2] + b, s3 = acc[c][3] + b;
        s0 = s0 >= 0.f ? s0 : al * s0;
        s1 = s1 >= 0.f ? s1 : al * s1;
        s2 = s2 >= 0.f ? s2 : al * s2;
        s3 = s3 >= 0.f ? s3 : al * s3;
        o[c] = __float2bfloat16(fmaxf(fmaxf(s0, s1), fmaxf(s2, s3)));
    }
    #pragma unroll
    for (int c = 10; c < 16; c++) o[c] = __float2bfloat16(0.f);

    float4* dst = (float4*)(p16 + (((size_t)n * PH + ph) * PH + pw) * 16);
    dst[0] = ((float4*)o)[0];
    dst[1] = ((float4*)o)[1];
}

// ---------------------------------------------------------------------------
// Stage 2: conv2 3x3 (16pad->16) + bias + PReLU, MFMA 16x16x32 bf16.
// A = weights (M=16 c_out, register-resident), B = pixels (N=16 px) -> D has
// col=px, row=c_out, so the NHWC store is 512 B fully-coalesced per tile
// (lane writes px=(lane&15)'s ch-quad (lane>>4)*4 as one 8 B chunk).
// K=32 = 2 taps x 16ch(10 real); 9 taps -> 5 K-steps, last half zero-padded.
// Wave = 64 px of one output row (4 tiles), 20 MFMA, 18 x 16 B B-loads/lane.
// grid: (ceil(357/64)=6, ceil(357/4)=90, 16), block 256. No barriers.
// ---------------------------------------------------------------------------
__global__ __launch_bounds__(256)
void conv2_mfma_kernel(const __hip_bfloat16* __restrict__ p16,
                       const float* __restrict__ ws,
                       const float* __restrict__ b2,
                       const float* __restrict__ a2,
                       __hip_bfloat16* __restrict__ c2h) {
    int wv = threadIdx.x >> 6;
    int l  = threadIdx.x & 63;
    int oh  = blockIdx.y * 4 + wv;
    int ow0 = blockIdx.x * 64;
    int n   = blockIdx.z;
    if (oh >= H2) return;

    int pxl = l & 15;          // B col: px within tile
    int q   = l >> 4;
    int taph = q >> 1;         // which tap within K-step
    int choff = (q & 1) << 3;  // channel sub-chunk

    const bf16x8* aw = (const bf16x8*)(ws + AW2_OFF);
    bf16x8 afr[5];
    #pragma unroll
    for (int s = 0; s < 5; s++) afr[s] = aw[s * 64 + l];

    bf16x8 zf;
    #pragma unroll
    for (int j = 0; j < 8; j++) zf[j] = 0;

    f32x4 acc[4];
    #pragma unroll
    for (int t = 0; t < 4; t++)
        #pragma unroll
        for (int i = 0; i < 4; i++) acc[t][i] = 0.f;

    #pragma unroll
    for (int s = 0; s < 5; s++) {
        int tap = 2 * s + taph;
        bool real = (tap < 9);
        int kh = tap / 3, kw = tap - kh * 3;
        int ih = oh + kh; if (ih > PH - 1) ih = PH - 1;   // only pad-tap can exceed
        #pragma unroll
        for (int t = 0; t < 4; t++) {
            int iw = ow0 + t * 16 + pxl + kw; if (iw > PH - 1) iw = PH - 1;
            const bf16x8* bp = (const bf16x8*)(p16 + (((size_t)n * PH + ih) * PH + iw) * 16 + choff);
            bf16x8 b = real ? *bp : zf;
            acc[t] = __builtin_amdgcn_mfma_f32_16x16x32_bf16(afr[s], b, acc[t], 0, 0, 0);
        }
    }

    // epilogue: bias+PReLU; lane's elements are (c_out = q*4+r, px = pxl)
    float bb[4], aa[4];
    #pragma unroll
    for (int r = 0; r < 4; r++) { bb[r] = b2[q * 4 + r]; aa[r] = a2[q * 4 + r]; }

    #pragma unroll
    for (int t = 0; t < 4; t++) {
        int px = ow0 + t * 16 + pxl;
        if (px < H2) {
            ushort4v pk;
            #pragma unroll
            for (int r = 0; r < 4; r++) {
                float v = acc[t][r] + bb[r];
                v = v >= 0.f ? v : aa[r] * v;
                __hip_bfloat16 h = __float2bfloat16(v);
                pk[r] = *(unsigned short*)&h;
            }
            *(ushort4v*)(c2h + (((size_t)n * H2 + oh) * H2 + px) * 16 + q * 4) = pk;
        }
    }
}

// ---------------------------------------------------------------------------
// Stage 3: conv3 3x3 (16->32) + PReLU + heads, MFMA 32x32x16 bf16 (R3,
// verified). A = pixels, B = weights; heads via stride-33 LDS; softmax.
// grid: (12, 45, 16), block 256
// ---------------------------------------------------------------------------
__global__ __launch_bounds__(256, 1)
void conv3_heads_kernel(const __hip_bfloat16* __restrict__ c2h,
                        const float* __restrict__ ws,
                        const float* __restrict__ b3,
                        const float* __restrict__ a3,
                        const float* __restrict__ w41,
                        const float* __restrict__ b41,
                        const float* __restrict__ w42,
                        const float* __restrict__ b42,
                        float* __restrict__ out) {
    int wv = threadIdx.x >> 6;
    int l  = threadIdx.x & 63;
    int ow0 = blockIdx.x * 32;
    int oh0 = blockIdx.y * 8 + wv * 2;
    int n   = blockIdx.z;

    int m    = l & 31;
    int half = l >> 5;
    int choff = half << 3;

    const bf16x8* bw = (const bf16x8*)(ws + BW3_OFF);
    bf16x8 bfr[9];
    #pragma unroll
    for (int t = 0; t < 9; t++) bfr[t] = bw[t * 64 + l];

    f32x16 acc0, acc1;
    #pragma unroll
    for (int i = 0; i < 16; i++) { acc0[i] = 0.f; acc1[i] = 0.f; }

    #pragma unroll
    for (int kh = 0; kh < 3; kh++) {
        int ih0 = oh0 + kh;     if (ih0 > H2 - 1) ih0 = H2 - 1;
        int ih1 = oh0 + 1 + kh; if (ih1 > H2 - 1) ih1 = H2 - 1;
        #pragma unroll
        for (int kw = 0; kw < 3; kw++) {
            int iw = ow0 + m + kw; if (iw > H2 - 1) iw = H2 - 1;
            const bf16x8* a0p = (const bf16x8*)(c2h + ((((size_t)n * H2 + ih0) * H2 + iw) << 4) + choff);
            const bf16x8* a1p = (const bf16x8*)(c2h + ((((size_t)n * H2 + ih1) * H2 + iw) << 4) + choff);
            bf16x8 a0 = *a0p;
            bf16x8 a1 = *a1p;
            int tap = kh * 3 + kw;
            acc0 = __builtin_amdgcn_mfma_f32_32x32x16_bf16(a0, bfr[tap], acc0, 0, 0, 0);
            acc1 = __builtin_amdgcn_mfma_f32_32x32x16_bf16(a1, bfr[tap], acc1, 0, 0, 0);
        }
    }

    __shared__ float hbuf[4][64 * 33];
    float* hb = hbuf[wv];
    float bb = b3[m], aa = a3[m];
    #pragma unroll
    for (int t = 0; t < 2; t++) {
        #pragma unroll
        for (int r = 0; r < 16; r++) {
            int mprime = (r & 3) + ((r >> 2) << 3) + (half << 2);
            float v = (t ? acc1[r] : acc0[r]) + bb;
            v = v >= 0.f ? v : aa * v;
            hb[(t * 32 + mprime) * 33 + m] = v;
        }
    }
    __syncthreads();

    int poh = oh0 + (l >> 5);
    int pow_ = ow0 + (l & 31);
    float h[32];
    #pragma unroll
    for (int c = 0; c < 32; c++) h[c] = hb[l * 33 + c];

    float l0 = b41[0], l1 = b41[1];
    float r0 = b42[0], r1 = b42[1], r2 = b42[2], r3 = b42[3];
    #pragma unroll
    for (int c = 0; c < 32; c++) {
        float hv = h[c];
        l0 = fmaf(hv, w41[c],      l0);
        l1 = fmaf(hv, w41[32 + c], l1);
        r0 = fmaf(hv, w42[c],      r0);
        r1 = fmaf(hv, w42[32 + c], r1);
        r2 = fmaf(hv, w42[64 + c], r2);
        r3 = fmaf(hv, w42[96 + c], r3);
    }
    float mx  = fmaxf(l0, l1);
    float e0 = __expf(l0 - mx), e1 = __expf(l1 - mx);
    float inv = 1.0f / (e0 + e1);

    if (poh < H3 && pow_ < H3) {
        const size_t sp = (size_t)H3 * H3;
        size_t pos = (size_t)poh * H3 + pow_;
        float* reg  = out;
        float* prob = out + (size_t)16 * 4 * sp;
        reg[((size_t)(n * 4 + 0)) * sp + pos] = r0;
        reg[((size_t)(n * 4 + 1)) * sp + pos] = r1;
        reg[((size_t)(n * 4 + 2)) * sp + pos] = r2;
        reg[((size_t)(n * 4 + 3)) * sp + pos] = r3;
        prob[((size_t)(n * 2 + 0)) * sp + pos] = e0 * inv;
        prob[((size_t)(n * 2 + 1)) * sp + pos] = e1 * inv;
    }
}

extern "C" void kernel_launch(void* const* d_in, const int* in_sizes, int n_in,
                              void* d_out, int out_size, void* d_ws, size_t ws_size,
                              hipStream_t stream) {
    const float* x   = (const float*)d_in[0];
    const float* w1  = (const float*)d_in[1];
    const float* b1  = (const float*)d_in[2];
    const float* a1  = (const float*)d_in[3];
    const float* w2  = (const float*)d_in[4];
    const float* b2  = (const float*)d_in[5];
    const float* a2  = (const float*)d_in[6];
    const float* w3  = (const float*)d_in[7];
    const float* b3  = (const float*)d_in[8];
    const float* a3  = (const float*)d_in[9];
    const float* w41 = (const float*)d_in[10];
    const float* b41 = (const float*)d_in[11];
    const float* w42 = (const float*)d_in[12];
    const float* b42 = (const float*)d_in[13];
    float* out = (float*)d_out;
    float* ws  = (float*)d_ws;

    __hip_bfloat16* p16 = (__hip_bfloat16*)(ws + P16_OFF);
    __hip_bfloat16* c2h = (__hip_bfloat16*)(ws + C2H_OFF);

    repack_kernel<<<1, 256, 0, stream>>>(w1, b1, w2, w3, ws);

    {
        dim3 grid((PH + 127) / 128, PH, 16);
        conv1_pool_kernel<<<grid, 128, 0, stream>>>(x, ws, a1, p16);
    }
    {
        dim3 grid((H2 + 63) / 64, (H2 + 3) / 4, 16);
        conv2_mfma_kernel<<<grid, 256, 0, stream>>>(p16, ws, b2, a2, c2h);
    }
    {
        dim3 grid((H3 + 31) / 32, (H3 + 7) / 8, 16);
        conv3_heads_kernel<<<grid, 256, 0, stream>>>(c2h, ws, b3, a3,
                                                     w41, b41, w42, b42, out);
    }
}